// Round 1
// baseline (139.772 us; speedup 1.0000x reference)
//
#include <hip/hip_runtime.h>

// Fused deformable-conv net — global-cell decomposition.
// r13 change vs r10 champion: blocks no longer map 1:1 to images with
// if(tid<196) (which ran wave 3 at 4/64 lanes => 23.4% of VALU issue
// wasted in a 95%-VALUBusy kernel). Cells are numbered globally
// (B*196 = 802816 = 3136 * 256, no tail); each block stages the <=3
// images its 256 cells touch (LDS 3*930 floats) and every lane is
// active in the main loop. Images span blocks -> out is memset to 0 in
// kernel_launch and blocks atomicAdd their partials (<=2 adds per
// output element; owner block of cell 0 folds in b_fc exactly once).
// Wave reduction is image-segmented: a wave spans <=2 images (196>64);
// straddling waves (wave-uniform test, scalar branch) run a dual
// butterfly. Secondary change: LDS image row stride 30 -> 31 floats
// (odd stride to spread gather banks; watch SQ_LDS_BANK_CONFLICT).
// Main compute body (offset conv, med3 clamps, factored bilinear,
// k-outer/p-inner acc[4][8], o-outer FC) is unchanged from r10.

#define HH 28
#define WW 28
#define WPL 31            // LDS row stride (odd => spread banks)
#define IMG_LDS 930       // 30 rows * 31
#define NPOS 784
#define NPOOL 1568
#define CELLS 196
#define TPB 256

__global__ __launch_bounds__(256) void deform_net_kernel(
    const float* __restrict__ x,       // (B,1,28,28)
    const float* __restrict__ w_off,   // (18,1,3,3)
    const float* __restrict__ b_off,   // (18,)
    const float* __restrict__ w_conv,  // (8,1,3,3)
    const float* __restrict__ w_fc,    // (10,1568)
    const float* __restrict__ b_fc,    // (10,)
    float* __restrict__ out,           // (B,10), pre-zeroed
    int Btot)
{
    __shared__ float xs[3 * IMG_LDS];  // up to 3 padded images
    __shared__ float wo_s[162];
    __shared__ float bo_s[18];
    __shared__ float wc_s[72];
    __shared__ float red[4][3][10];    // [wave][image-slot][channel]

    const int tid   = threadIdx.x;
    const int cell0 = blockIdx.x * TPB;
    const int imgFirst = cell0 / CELLS;
    const int total = Btot * CELLS;

    if (tid < 162) wo_s[tid] = w_off[tid];
    if (tid < 18)  bo_s[tid] = b_off[tid];
    if (tid < 72)  wc_s[tid] = w_conv[tid];
    if (tid < 120) (&red[0][0][0])[tid] = 0.f;

    // Stage the (up to) 3 zero-padded images this block's cells touch.
    for (int i = tid; i < 3 * 900; i += TPB) {
        int s = i / 900, v = i - s * 900;
        int img = imgFirst + s;
        int r = v / 30, c = v - r * 30;
        float val = 0.f;
        if (img < Btot && r >= 1 && r <= HH && c >= 1 && c <= WW)
            val = x[(size_t)img * NPOS + (r - 1) * WW + (c - 1)];
        xs[s * IMG_LDS + r * WPL + c] = val;
    }
    __syncthreads();

    const int cell = cell0 + tid;
    const int img  = cell / CELLS;          // magic-mul div, once
    const int cim  = cell - img * CELLS;
    const int slot = img - imgFirst;        // 0..2
    const float* xsl = xs + slot * IMG_LDS;

    float fc[10];
    #pragma unroll
    for (int c = 0; c < 10; c++) fc[c] = 0.f;

    if (cell < total) {
        const int ph = cim / 14, pw = cim - (cim / 14) * 14;
        const int h0 = 2 * ph, w0 = 2 * pw;

        // 4x4 padded-image neighborhood covering all 4 positions' 3x3 taps.
        float nb[16];
        #pragma unroll
        for (int i = 0; i < 4; i++)
            #pragma unroll
            for (int j = 0; j < 4; j++)
                nb[i * 4 + j] = xsl[(h0 + i) * WPL + (w0 + j)];

        float acc[4][8];
        #pragma unroll
        for (int p = 0; p < 4; p++)
            #pragma unroll
            for (int o = 0; o < 8; o++) acc[p][o] = 0.f;

        #pragma unroll
        for (int k = 0; k < 9; k++) {          // deform tap
            const int kx = k / 3, ky = k % 3;
            #pragma unroll
            for (int p = 0; p < 4; p++) {      // position within pool cell
                const int dh = p >> 1, dw = p & 1;

                // offset channels k (x) and k+9 (y): 3x3 conv at (h0+dh, w0+dw)
                float offx = bo_s[k], offy = bo_s[k + 9];
                #pragma unroll
                for (int t = 0; t < 9; t++) {
                    float nv = nb[(dh + t / 3) * 4 + (dw + t % 3)];
                    offx = fmaf(wo_s[k * 9 + t],       nv, offx);
                    offy = fmaf(wo_s[(k + 9) * 9 + t], nv, offy);
                }

                // sample coords in padded frame: p0=(h+1,w+1), pn=(kx-1,ky-1)
                float p_x = (float)(h0 + dh + kx) + offx;
                float p_y = (float)(w0 + dw + ky) + offy;

                float q0x = floorf(p_x), q0y = floorf(p_y);
                float qltx = __builtin_amdgcn_fmed3f(q0x,       0.f, 29.f);
                float qlty = __builtin_amdgcn_fmed3f(q0y,       0.f, 29.f);
                float qrbx = __builtin_amdgcn_fmed3f(q0x + 1.f, 0.f, 29.f);
                float qrby = __builtin_amdgcn_fmed3f(q0y + 1.f, 0.f, 29.f);
                float px   = __builtin_amdgcn_fmed3f(p_x,       0.f, 29.f);
                float py   = __builtin_amdgcn_fmed3f(p_y,       0.f, 29.f);

                float gltx = 1.f + (qltx - px);
                float glty = 1.f + (qlty - py);
                float grbx = 1.f - (qrbx - px);
                float grby = 1.f - (qrby - py);

                int ilx = (int)qltx, ily = (int)qlty;
                int irx = (int)qrbx, iry = (int)qrby;

                float xlt = xsl[ilx * WPL + ily];
                float xrb = xsl[irx * WPL + iry];
                float xlb = xsl[ilx * WPL + iry];
                float xrt = xsl[irx * WPL + ily];

                // factored bilinear combine (same clip semantics)
                float s = gltx * (glty * xlt + grby * xlb)
                        + grbx * (glty * xrt + grby * xrb);

                #pragma unroll
                for (int o = 0; o < 8; o++)
                    acc[p][o] = fmaf(wc_s[o * 9 + k], s, acc[p][o]);
            }
        }

        // relu + 2x2 maxpool in registers, then FC partial sums (o-outer).
        #pragma unroll
        for (int o = 0; o < 8; o++) {
            float m = fmaxf(fmaxf(acc[0][o], acc[1][o]),
                            fmaxf(acc[2][o], acc[3][o]));
            m = fmaxf(m, 0.f);
            const float* wrow = w_fc + o * CELLS + cim;  // flat idx o*196+cell
            #pragma unroll
            for (int c = 0; c < 10; c++)
                fc[c] = fmaf(m, wrow[c * NPOOL], fc[c]);
        }
    }

    // Image-segmented wave reduction. A wave's 64 consecutive cells span
    // at most 2 images. sLo/sHi are wave-uniform scalars.
    const int wave = tid >> 6, lane = tid & 63;
    const int wc0 = cell0 + (wave << 6);
    const int sLo = wc0 / CELLS - imgFirst;
    const int sHi = (wc0 + 63) / CELLS - imgFirst;

    if (sLo == sHi) {
        #pragma unroll
        for (int c = 0; c < 10; c++)
            #pragma unroll
            for (int sh = 32; sh > 0; sh >>= 1)
                fc[c] += __shfl_down(fc[c], sh, 64);
        if (lane == 0) {
            #pragma unroll
            for (int c = 0; c < 10; c++) red[wave][sLo][c] = fc[c];
        }
    } else {
        float va[10];
        const bool lo = (slot == sLo);
        #pragma unroll
        for (int c = 0; c < 10; c++) {
            va[c] = lo ? fc[c] : 0.f;
            fc[c] = lo ? 0.f : fc[c];
        }
        #pragma unroll
        for (int c = 0; c < 10; c++)
            #pragma unroll
            for (int sh = 32; sh > 0; sh >>= 1) {
                va[c] += __shfl_down(va[c], sh, 64);
                fc[c] += __shfl_down(fc[c], sh, 64);
            }
        if (lane == 0) {
            #pragma unroll
            for (int c = 0; c < 10; c++) {
                red[wave][sLo][c] = va[c];
                red[wave][sHi][c] = fc[c];
            }
        }
    }
    __syncthreads();

    // Cross-wave sum per (image-slot, channel); owner block folds b_fc.
    if (tid < 30) {
        const int s = tid / 10, c = tid - (tid / 10) * 10;
        const int oimg = imgFirst + s;
        if (oimg < Btot) {
            float v = red[0][s][c] + red[1][s][c]
                    + red[2][s][c] + red[3][s][c];
            const int c0im = oimg * CELLS - cell0;
            if (c0im >= 0 && c0im < TPB) v += b_fc[c];   // exactly one owner
            if (v != 0.f) atomicAdd(out + oimg * 10 + c, v);
        }
    }
}

extern "C" void kernel_launch(void* const* d_in, const int* in_sizes, int n_in,
                              void* d_out, int out_size, void* d_ws, size_t ws_size,
                              hipStream_t stream) {
    const float* x      = (const float*)d_in[0];
    const float* w_off  = (const float*)d_in[1];
    const float* b_off  = (const float*)d_in[2];
    const float* w_conv = (const float*)d_in[3];
    const float* w_fc   = (const float*)d_in[4];
    const float* b_fc   = (const float*)d_in[5];
    float* out = (float*)d_out;

    const int B = in_sizes[0] / NPOS;
    hipMemsetAsync(d_out, 0, (size_t)B * 10 * sizeof(float), stream);
    const int nblk = (B * CELLS + TPB - 1) / TPB;   // 3136 for B=4096, no tail
    deform_net_kernel<<<nblk, TPB, 0, stream>>>(x, w_off, b_off, w_conv,
                                                w_fc, b_fc, out, B);
}